// Round 3
// baseline (764.095 us; speedup 1.0000x reference)
//
#include <hip/hip_runtime.h>
#include <hip/hip_bf16.h>

// Bilinear resample, zero-padding OOB semantics.
// imgs: (B,H,W,1) f32, dvfs: (B,H,W,2) f32 (ch0 = x offset, ch1 = y offset)
// out:  (B,H,W,1) f32.  B=32, H=W=1024.
//
// R3: R1 structure (natural 1D block order — preserves emergent all-XCDs-
// same-image L3 locality) but 8 px/thread for 2x memory-level parallelism:
// 4 dvfs float4 loads + 32 independent gathers in flight per thread.

#define H_DIM 1024
#define W_DIM 1024
#define HW    (H_DIM * W_DIM)
#define PX_PER_THREAD 8

typedef float vf4 __attribute__((ext_vector_type(4)));

__device__ __forceinline__ float gather_zp(const float* __restrict__ img,
                                           int yy, int xx) {
    bool valid = (xx >= 0) & (xx < W_DIM) & (yy >= 0) & (yy < H_DIM);
    int xc = min(max(xx, 0), W_DIM - 1);
    int yc = min(max(yy, 0), H_DIM - 1);
    float v = img[yc * W_DIM + xc];
    return valid ? v : 0.0f;
}

__global__ __launch_bounds__(256) void bilerp_kernel(
        const float* __restrict__ imgs,
        const float* __restrict__ dvfs,
        float* __restrict__ out) {
    size_t tid  = (size_t)blockIdx.x * blockDim.x + threadIdx.x;
    size_t base = tid * PX_PER_THREAD;   // 8 consecutive px, same row (W%8==0)

    int b   = (int)(base >> 20);         // /HW
    int rem = (int)(base & (HW - 1));
    int y   = rem >> 10;                 // /W_DIM
    int x   = rem & (W_DIM - 1);

    const float* __restrict__ img = imgs + (size_t)b * HW;

    // 16 dvfs floats for 8 px: four coalesced float4 loads
    const vf4* dvf4 = (const vf4*)(dvfs + base * 2);
    vf4 d0 = dvf4[0];
    vf4 d1 = dvf4[1];
    vf4 d2 = dvf4[2];
    vf4 d3 = dvf4[3];
    float dx[8] = {d0.x, d0.z, d1.x, d1.z, d2.x, d2.z, d3.x, d3.z};
    float dy[8] = {d0.y, d0.w, d1.y, d1.w, d2.y, d2.w, d3.y, d3.w};

    float res[8];
    #pragma unroll
    for (int i = 0; i < 8; ++i) {
        float fx = (float)(x + i) + dx[i];
        float fy = (float)y       + dy[i];
        float x0f = floorf(fx);
        float y0f = floorf(fy);
        float wx = fx - x0f;
        float wy = fy - y0f;
        int x0 = (int)x0f;
        int y0 = (int)y0f;
        int x1 = x0 + 1;
        int y1 = y0 + 1;

        float v00 = gather_zp(img, y0, x0);
        float v01 = gather_zp(img, y0, x1);
        float v10 = gather_zp(img, y1, x0);
        float v11 = gather_zp(img, y1, x1);

        res[i] = v00 * (1.0f - wx) * (1.0f - wy)
               + v01 * wx          * (1.0f - wy)
               + v10 * (1.0f - wx) * wy
               + v11 * wx          * wy;
    }

    vf4 r0 = {res[0], res[1], res[2], res[3]};
    vf4 r1 = {res[4], res[5], res[6], res[7]};
    ((vf4*)(out + base))[0] = r0;
    ((vf4*)(out + base))[1] = r1;
}

extern "C" void kernel_launch(void* const* d_in, const int* in_sizes, int n_in,
                              void* d_out, int out_size, void* d_ws, size_t ws_size,
                              hipStream_t stream) {
    const float* imgs = (const float*)d_in[0];
    const float* dvfs = (const float*)d_in[1];
    float* out = (float*)d_out;

    int n_threads = out_size / PX_PER_THREAD;          // 4,194,304
    int nblocks = (n_threads + 255) / 256;             // 16,384

    bilerp_kernel<<<nblocks, 256, 0, stream>>>(imgs, dvfs, out);
}